// Round 6
// baseline (106.416 us; speedup 1.0000x reference)
//
#include <hip/hip_runtime.h>

#define SIZE 128
#define T_PER_BLK 4   // tiles (64 rows) per block: 4096/4 = 1024 blocks = 4/CU exact

typedef short short8 __attribute__((ext_vector_type(8)));
typedef float f32x4 __attribute__((ext_vector_type(4)));

__device__ __forceinline__ unsigned short f2bf(float f) {
    unsigned int u = __float_as_uint(f);
    unsigned int r = u + 0x7FFFu + ((u >> 16) & 1u);
    return (unsigned short)(r >> 16);
}

// Build Gt[n][k] = gr[(n-k) & 127] in bf16, gr = Re(ifft(b)). Packed u32 stores.
__global__ void build_gt(const float* __restrict__ br, const float* __restrict__ bi,
                         unsigned int* __restrict__ Gt) {
    __shared__ float gr[SIZE];
    const int t = threadIdx.x;  // 0..127
    float acc = 0.0f;
    for (int j = 0; j < SIZE; ++j) {
        int p = (j * t) & 127;                 // exact periodic reduction
        float a = (float)p * (1.0f / 64.0f);   // angle in units of pi
        acc += br[j] * cospif(a) - bi[j] * sinpif(a);
    }
    gr[t] = acc * (1.0f / 128.0f);
    __syncthreads();
    for (int k2 = 0; k2 < 64; ++k2) {
        unsigned int lo = f2bf(gr[(t - 2 * k2) & 127]);
        unsigned int hi = f2bf(gr[(t - 2 * k2 - 1) & 127]);
        Gt[t * 64 + k2] = lo | (hi << 16);
    }
}

// out[m][n] = sum_k h[m][k]*Gt[n][k] + x[m][n], h = tanh(alpha*x)*w + bias.
// 256 threads / 4 waves; wave w owns cols [32w,32w+32). 4 tiles per block
// (1024 blocks = 4 resident/CU for cross-block latency overlap), double-
// buffered LDS h, 1 barrier/tile, x prefetched 1 tile ahead in regs.
__global__ __launch_bounds__(256, 4) void fourier_main(
    const float* __restrict__ x, const float* __restrict__ alpha_p,
    const float* __restrict__ w, const float* __restrict__ bias,
    const unsigned short* __restrict__ Gt, float* __restrict__ out) {
    __shared__ unsigned short hA[2][64][136];  // +8 pad breaks pow2 stride

    const int tid = threadIdx.x;
    const int lane = tid & 63;
    const int wid = tid >> 6;
    const int lrow = lane & 15;      // fragment row
    const int slot = lane >> 4;      // k-chunk / col-group selector
    const int cg = slot * 4;
    const int colb = wid * 32;

    const float a2 = 2.0f * alpha_p[0];

    // per-thread DyT params for its two column groups
    float4 w4[2], b4[2];
#pragma unroll
    for (int nt = 0; nt < 2; ++nt) {
        const int c = colb + nt * 16 + cg;
        w4[nt] = *reinterpret_cast<const float4*>(&w[c]);
        b4[nt] = *reinterpret_cast<const float4*>(&bias[c]);
    }

    // G fragments: loaded ONCE per block (L2-resident 32 KB), reused all tiles
    short8 gf[2][4];
#pragma unroll
    for (int nt = 0; nt < 2; ++nt) {
        const int n = colb + nt * 16 + lrow;
#pragma unroll
        for (int kt = 0; kt < 4; ++kt) {
            gf[nt][kt] = *reinterpret_cast<const short8*>(
                &Gt[n * SIZE + kt * 32 + slot * 8]);
        }
    }

    // 32-bit element offsets (max 33.5M < 2^31)
    const unsigned tile0 = (unsigned)blockIdx.x * (T_PER_BLK * 64u * SIZE);
    unsigned soff[4][2];  // thread's static (row,col) footprint within a tile
#pragma unroll
    for (int mt = 0; mt < 4; ++mt)
#pragma unroll
        for (int nt = 0; nt < 2; ++nt)
            soff[mt][nt] = (mt * 16 + lrow) * SIZE + colb + nt * 16 + cg;

    float4 xA[4][2], xB[4][2];

    // DyT pipeline stage: fp32 x -> bf16 h (packed ushort4)
    auto hquad = [&](const float4 xv, int nt) -> ushort4 {
        ushort4 hq;
        float t, e, r, th;
        t = a2 * xv.x; e = __expf(t); r = __builtin_amdgcn_rcpf(1.0f + e);
        th = fmaf(-2.0f, r, 1.0f); hq.x = f2bf(fmaf(th, w4[nt].x, b4[nt].x));
        t = a2 * xv.y; e = __expf(t); r = __builtin_amdgcn_rcpf(1.0f + e);
        th = fmaf(-2.0f, r, 1.0f); hq.y = f2bf(fmaf(th, w4[nt].y, b4[nt].y));
        t = a2 * xv.z; e = __expf(t); r = __builtin_amdgcn_rcpf(1.0f + e);
        th = fmaf(-2.0f, r, 1.0f); hq.z = f2bf(fmaf(th, w4[nt].z, b4[nt].z));
        t = a2 * xv.w; e = __expf(t); r = __builtin_amdgcn_rcpf(1.0f + e);
        th = fmaf(-2.0f, r, 1.0f); hq.w = f2bf(fmaf(th, w4[nt].w, b4[nt].w));
        return hq;
    };

    // ---- prologue: tile 0 -> xA, h(0) -> buf 0 ----
#pragma unroll
    for (int mt = 0; mt < 4; ++mt)
#pragma unroll
        for (int nt = 0; nt < 2; ++nt)
            xA[mt][nt] = *reinterpret_cast<const float4*>(&x[tile0 + soff[mt][nt]]);
#pragma unroll
    for (int mt = 0; mt < 4; ++mt)
#pragma unroll
        for (int nt = 0; nt < 2; ++nt)
            *reinterpret_cast<ushort4*>(
                &hA[0][mt * 16 + lrow][colb + nt * 16 + cg]) = hquad(xA[mt][nt], nt);
    __syncthreads();

    // ---- pipelined tile loop: body(t) reads buf pp, writes buf pp^1 ----
    auto body = [&](int tt, float4 (&xc)[4][2], float4 (&xn)[4][2], int pp)
        __attribute__((always_inline)) {
        const unsigned tbase = tile0 + (unsigned)tt * (64u * SIZE);
        const bool pf = (tt + 1) < T_PER_BLK;

        // 1. prefetch next tile's x (latency hidden under MFMA + stores)
        if (pf) {
#pragma unroll
            for (int mt = 0; mt < 4; ++mt)
#pragma unroll
                for (int nt = 0; nt < 2; ++nt)
                    xn[mt][nt] = *reinterpret_cast<const float4*>(
                        &x[tbase + 64u * SIZE + soff[mt][nt]]);
        }

        // 2. MFMA on current buffer. Swapped operands: acc regs = 4 output cols.
        f32x4 acc[4][2];
#pragma unroll
        for (int mt = 0; mt < 4; ++mt) {
            short8 hf[4];
#pragma unroll
            for (int kt = 0; kt < 4; ++kt)
                hf[kt] = *reinterpret_cast<const short8*>(
                    &hA[pp][mt * 16 + lrow][kt * 32 + slot * 8]);
#pragma unroll
            for (int nt = 0; nt < 2; ++nt) {
                f32x4 a = {0.f, 0.f, 0.f, 0.f};
#pragma unroll
                for (int kt = 0; kt < 4; ++kt)
                    a = __builtin_amdgcn_mfma_f32_16x16x32_bf16(gf[nt][kt], hf[kt],
                                                                a, 0, 0, 0);
                acc[mt][nt] = a;
            }
        }

        // 3. h(t+1) -> other buffer (different buffer than step-2 reads)
        if (pf) {
#pragma unroll
            for (int mt = 0; mt < 4; ++mt)
#pragma unroll
                for (int nt = 0; nt < 2; ++nt)
                    *reinterpret_cast<ushort4*>(
                        &hA[pp ^ 1][mt * 16 + lrow][colb + nt * 16 + cg]) =
                        hquad(xn[mt][nt], nt);
        }

        // 4. epilogue: regular float4 stores (L2 merges the 64B halves per line)
#pragma unroll
        for (int mt = 0; mt < 4; ++mt)
#pragma unroll
            for (int nt = 0; nt < 2; ++nt) {
                float4 r;
                r.x = acc[mt][nt][0] + xc[mt][nt].x;
                r.y = acc[mt][nt][1] + xc[mt][nt].y;
                r.z = acc[mt][nt][2] + xc[mt][nt].z;
                r.w = acc[mt][nt][3] + xc[mt][nt].w;
                *reinterpret_cast<float4*>(&out[tbase + soff[mt][nt]]) = r;
            }

        // 5. one barrier/tile: publishes buf pp^1, retires all reads of buf pp
        if (pf) __syncthreads();
    };

#pragma unroll
    for (int t = 0; t < T_PER_BLK; t += 2) {
        body(t, xA, xB, 0);
        body(t + 1, xB, xA, 1);
    }
}

extern "C" void kernel_launch(void* const* d_in, const int* in_sizes, int n_in,
                              void* d_out, int out_size, void* d_ws, size_t ws_size,
                              hipStream_t stream) {
    const float* x = (const float*)d_in[0];
    const float* alpha = (const float*)d_in[1];
    const float* dyt_w = (const float*)d_in[2];
    const float* dyt_b = (const float*)d_in[3];
    // d_in[4] = a_real, d_in[5] = a_imag, d_in[8] = ffn_bias: dead code in reference
    const float* b_real = (const float*)d_in[6];
    const float* b_imag = (const float*)d_in[7];
    float* out = (float*)d_out;

    build_gt<<<1, 128, 0, stream>>>(b_real, b_imag, (unsigned int*)d_ws);

    const int rows = out_size / SIZE;                 // 262144
    const int nblocks = rows / (64 * T_PER_BLK);      // 1024
    fourier_main<<<nblocks, 256, 0, stream>>>(x, alpha, dyt_w, dyt_b,
                                              (const unsigned short*)d_ws, out);
}

// Round 7
// 71.012 us; speedup vs baseline: 1.4986x; 1.4986x over previous
//
#include <hip/hip_runtime.h>

#define SIZE 128
#define PAD 136   // LDS row pitch in bf16 elements; breaks pow2 stride

typedef short short8 __attribute__((ext_vector_type(8)));
typedef float f32x4 __attribute__((ext_vector_type(4)));

__device__ __forceinline__ unsigned short f2bf(float f) {
    unsigned int u = __float_as_uint(f);
    unsigned int r = u + 0x7FFFu + ((u >> 16) & 1u);
    return (unsigned short)(r >> 16);
}
__device__ __forceinline__ float bf2f(unsigned short h) {
    return __uint_as_float(((unsigned int)h) << 16);
}

// gr = Re(ifft(b)). Folds DyT affine params into the conv matrix:
//   Gt[c][k] = w[k] * gr[(c-k)&127]   (bf16, 32 KB)
//   C0[c]    = sum_k bias[k] * gr[(c-k)&127]   (f32, 512 B at offset 32768)
__global__ void build_gt(const float* __restrict__ br, const float* __restrict__ bi,
                         const float* __restrict__ w, const float* __restrict__ bias,
                         unsigned short* __restrict__ Gt, float* __restrict__ C0) {
    __shared__ float gr[SIZE];
    const int t = threadIdx.x;  // 0..127
    float acc = 0.0f;
    for (int j = 0; j < SIZE; ++j) {
        int p = (j * t) & 127;                 // exact periodic reduction
        float a = (float)p * (1.0f / 64.0f);   // angle in units of pi
        acc += br[j] * cospif(a) - bi[j] * sinpif(a);
    }
    gr[t] = acc * (1.0f / 128.0f);
    __syncthreads();
    float c0 = 0.0f;
    for (int k = 0; k < SIZE; ++k) {
        const float g = gr[(t - k) & 127];
        c0 += bias[k] * g;
        Gt[t * SIZE + k] = f2bf(w[k] * g);
    }
    C0[t] = c0;
}

// out[r][c] = sum_k tanh(alpha*x[r][k]) * Gt[c][k] + C0[c] + x[r][c]
// 256 threads / 4 waves, one 64x128 tile per block (4096 blocks = 4/CU).
// ALL global accesses lane-contiguous (1 KB / wave-instruction); the
// linear<->fragment layout mismatch is bounced through LDS (hA in, oA out).
__global__ __launch_bounds__(256, 4) void fourier_main(
    const float* __restrict__ x, const float* __restrict__ alpha_p,
    const unsigned short* __restrict__ Gt, const float* __restrict__ C0,
    float* __restrict__ out) {
    __shared__ unsigned short hA[64 * PAD];  // bf16 tanh(alpha*x) tile
    __shared__ unsigned short oA[64 * PAD];  // bf16 conv+C0 tile

    const int tid = threadIdx.x;
    const int lane = tid & 63;
    const int wid = tid >> 6;
    const int lrow = lane & 15;   // fragment row selector
    const int slot = lane >> 4;   // fragment k-chunk / col-group selector
    const int colb = wid * 32;

    const float a2 = 2.0f * alpha_p[0];
    const unsigned base = (unsigned)blockIdx.x * (64u * SIZE);  // max 33.5M < 2^31

    // linear map: thread tid, pass j  <->  elements base + j*1024 + tid*4 .. +4
    const int rl = tid >> 5;        // row within 8-row group: tile row = j*8 + rl
    const int cl = (tid & 31) * 4;  // column of the 4-float group

    // ---- 1. load x contiguously, keep in regs ----
    float4 xr[8];
#pragma unroll
    for (int j = 0; j < 8; ++j)
        xr[j] = *reinterpret_cast<const float4*>(&x[base + j * 1024 + tid * 4]);

    // ---- 2. h = tanh(alpha*x) -> bf16 -> hA (w/bias folded into G/C0) ----
    // tanh(t) = 1 - 2/(1+e^{2t})
#pragma unroll
    for (int j = 0; j < 8; ++j) {
        ushort4 hq;
        float e, r;
        e = __expf(a2 * xr[j].x); r = __builtin_amdgcn_rcpf(1.0f + e);
        hq.x = f2bf(fmaf(-2.0f, r, 1.0f));
        e = __expf(a2 * xr[j].y); r = __builtin_amdgcn_rcpf(1.0f + e);
        hq.y = f2bf(fmaf(-2.0f, r, 1.0f));
        e = __expf(a2 * xr[j].z); r = __builtin_amdgcn_rcpf(1.0f + e);
        hq.z = f2bf(fmaf(-2.0f, r, 1.0f));
        e = __expf(a2 * xr[j].w); r = __builtin_amdgcn_rcpf(1.0f + e);
        hq.w = f2bf(fmaf(-2.0f, r, 1.0f));
        *reinterpret_cast<ushort4*>(&hA[(j * 8 + rl) * PAD + cl]) = hq;
    }

    // ---- G fragments (L2-resident 32 KB) + C0 for this thread's out cols ----
    short8 gf[2][4];
    float4 c0v[2];
#pragma unroll
    for (int nt = 0; nt < 2; ++nt) {
        const int c = colb + nt * 16 + lrow;
#pragma unroll
        for (int kt = 0; kt < 4; ++kt)
            gf[nt][kt] = *reinterpret_cast<const short8*>(
                &Gt[c * SIZE + kt * 32 + slot * 8]);
        c0v[nt] = *reinterpret_cast<const float4*>(&C0[colb + nt * 16 + slot * 4]);
    }

    __syncthreads();

    // ---- 3. MFMA per 16-row band; acc + C0 -> bf16 -> oA ----
#pragma unroll
    for (int mt = 0; mt < 4; ++mt) {
        short8 hf[4];
#pragma unroll
        for (int kt = 0; kt < 4; ++kt)
            hf[kt] = *reinterpret_cast<const short8*>(
                &hA[(mt * 16 + lrow) * PAD + kt * 32 + slot * 8]);
#pragma unroll
        for (int nt = 0; nt < 2; ++nt) {
            f32x4 a = {0.f, 0.f, 0.f, 0.f};
#pragma unroll
            for (int kt = 0; kt < 4; ++kt)
                a = __builtin_amdgcn_mfma_f32_16x16x32_bf16(gf[nt][kt], hf[kt], a,
                                                            0, 0, 0);
            // D: out row = 16mt + (lane&15); out cols = colb+16nt+4*slot + reg
            ushort4 o;
            o.x = f2bf(a[0] + c0v[nt].x);
            o.y = f2bf(a[1] + c0v[nt].y);
            o.z = f2bf(a[2] + c0v[nt].z);
            o.w = f2bf(a[3] + c0v[nt].w);
            *reinterpret_cast<ushort4*>(
                &oA[(mt * 16 + lrow) * PAD + colb + nt * 16 + slot * 4]) = o;
        }
    }

    __syncthreads();

    // ---- 4. epilogue: read oA linearly, add residual from regs, store 1KB/instr ----
#pragma unroll
    for (int j = 0; j < 8; ++j) {
        const ushort4 ov =
            *reinterpret_cast<const ushort4*>(&oA[(j * 8 + rl) * PAD + cl]);
        float4 r;
        r.x = bf2f(ov.x) + xr[j].x;
        r.y = bf2f(ov.y) + xr[j].y;
        r.z = bf2f(ov.z) + xr[j].z;
        r.w = bf2f(ov.w) + xr[j].w;
        *reinterpret_cast<float4*>(&out[base + j * 1024 + tid * 4]) = r;
    }
}

extern "C" void kernel_launch(void* const* d_in, const int* in_sizes, int n_in,
                              void* d_out, int out_size, void* d_ws, size_t ws_size,
                              hipStream_t stream) {
    const float* x = (const float*)d_in[0];
    const float* alpha = (const float*)d_in[1];
    const float* dyt_w = (const float*)d_in[2];
    const float* dyt_b = (const float*)d_in[3];
    // d_in[4] = a_real, d_in[5] = a_imag, d_in[8] = ffn_bias: dead code in reference
    const float* b_real = (const float*)d_in[6];
    const float* b_imag = (const float*)d_in[7];
    float* out = (float*)d_out;

    unsigned short* Gt = (unsigned short*)d_ws;            // 32 KB bf16
    float* C0 = (float*)((char*)d_ws + SIZE * SIZE * 2);   // 512 B f32

    build_gt<<<1, 128, 0, stream>>>(b_real, b_imag, dyt_w, dyt_b, Gt, C0);

    const int rows = out_size / SIZE;   // 262144
    const int nblocks = rows / 64;      // 4096
    fourier_main<<<nblocks, 256, 0, stream>>>(x, alpha, Gt, C0, out);
}